// Round 8
// baseline (4243.071 us; speedup 1.0000x reference)
//
#include <hip/hip_runtime.h>
#include <hip/hip_bf16.h>
#include <cmath>

#define DEV __device__ __forceinline__

constexpr int B_ = 8, S_ = 512, IN_ = 64, D_ = 512, L_ = 4;
constexpr int DI_ = 1024, DCONV_ = 4, DTR_ = 32;
constexpr int ROWS = B_ * S_;  // 4096

// ---------------- workspace arena (bytes) ----------------
constexpr size_t MB = 1ull << 20;
constexpr size_t OFF_X    = 0;              // x_cur   (4096,512) f32  8MB
constexpr size_t OFF_XN   = OFF_X   + 8*MB; // xn f16 / final-LN f32   8MB
constexpr size_t OFF_XZ   = OFF_XN  + 8*MB; // xz f16 (4096,2048) 16MB (region 32MB)
constexpr size_t OFF_XM   = OFF_XZ  + 32*MB;// xm f16 (4096,1024)  8MB (region 16MB)
constexpr size_t OFF_DT   = OFF_XM  + 16*MB;// (unused)            16MB
constexpr size_t OFF_XDBL = OFF_DT  + 16*MB;// x_dbl  (4096,64) f32 1MB
constexpr size_t OFF_YG   = OFF_XDBL+ 1*MB; // y_gated f16 (4096,1024) 8MB (region 16MB)
constexpr size_t OFF_MO   = OFF_YG  + 16*MB;// mamba_o (4096,512) f32  8MB
constexpr size_t OFF_WINT = OFF_MO  + 8*MB; // WinT    (512,64)        128KB
constexpr size_t OFF_MEAN = OFF_WINT+ 128*1024; // xmean (8,512)       16KB
constexpr size_t OFF_HBUF = OFF_MEAN+ 16*1024;  // hbuf [2][8][512]    32KB
constexpr size_t OFF_FLG  = OFF_HBUF+ 32*1024;  // flags 8*8*16 u32    4KB
constexpr size_t OFF_W16  = OFF_FLG + 64*1024;  // f16 weights 4 layers ~31MB
constexpr size_t OFF_BASIS= OFF_XZ;         // basis f16 (4096,4096) 32MB, aliases xz region

// per-layer f16 weight arena (element offsets)
constexpr size_t W_IP = 0;         // (2048,512)  1048576
constexpr size_t W_OP = 1048576;   // (512,1024)   524288
constexpr size_t W_KB = 1572864;   // (512,512)    262144
constexpr size_t W_KS = 1835008;   // (512,4096)  2097152
constexpr size_t W_XP = 3932160;   // (64,1024)     65536
constexpr size_t W_DT = 3997696;   // (1024,32)     32768 (unused now)
constexpr size_t W_PER_LAYER = 4030464;

// ---------------- math helpers ----------------
DEV float siluf(float x){ return x / (1.f + __expf(-x)); }
DEV float softplusf(float x){ return fmaxf(x, 0.f) + log1pf(__expf(-fabsf(x))); }
DEV unsigned short f2h(float f){ return __builtin_bit_cast(unsigned short, (_Float16)f); }
DEV float h2f(unsigned short u){ return (float)__builtin_bit_cast(_Float16, u); }
DEV int pk2(float a, float b){ return (int)((unsigned)f2h(a) | ((unsigned)f2h(b) << 16)); }

typedef _Float16 half8 __attribute__((ext_vector_type(8)));
typedef float f32x4 __attribute__((ext_vector_type(4)));

DEV void bspline8(float x, float* bb){
  const float h = 0.4f, g0 = -2.2f;
  float b0[11];
#pragma unroll
  for (int j = 0; j < 11; ++j){
    float gj  = g0 + h * j;
    float gj1 = g0 + h * (j + 1);
    b0[j] = (x >= gj && x < gj1) ? 1.f : 0.f;
  }
#pragma unroll
  for (int p = 1; p <= 3; ++p){
    float inv = 1.f / (h * p);
#pragma unroll
    for (int j = 0; j + p < 11; ++j){
      float gj  = g0 + h * j;
      float gip = g0 + h * (j + p + 1);
      b0[j] = (x - gj) * inv * b0[j] + (gip - x) * inv * b0[j + 1];
    }
  }
#pragma unroll
  for (int c = 0; c < 8; ++c) bb[c] = b0[c];
}

// ---------------- weight f32 -> f16 conversion (one layer) ----------------
__global__ __launch_bounds__(256)
void conv_w16(const float* __restrict__ ip, const float* __restrict__ op,
              const float* __restrict__ kb, const float* __restrict__ ks,
              const float* __restrict__ xp, unsigned short* __restrict__ w16)
{
  int blk = blockIdx.x, tid = threadIdx.x;
  const float* src; size_t doff; int sb;
  if      (blk < 512) { src = ip; doff = W_IP; sb = blk; }
  else if (blk < 768) { src = op; doff = W_OP; sb = blk - 512; }
  else if (blk < 896) { src = kb; doff = W_KB; sb = blk - 768; }
  else if (blk < 1920){ src = ks; doff = W_KS; sb = blk - 896; }
  else                { src = xp; doff = W_XP; sb = blk - 1920; }
  size_t e = (size_t)sb * 2048 + tid * 8;
  float4 a = *(const float4*)(src + e), b = *(const float4*)(src + e + 4);
  int4 v = { pk2(a.x,a.y), pk2(a.z,a.w), pk2(b.x,b.y), pk2(b.z,b.w) };
  *(int4*)&w16[doff + e] = v;
}

// ---------------- tiled f32 NT GEMM (initial x@WinT only) ----------------
template<bool SILU_A, int EPI>
__global__ __launch_bounds__(256)
void gemm_nt(const float* __restrict__ A, int lda,
             const float* __restrict__ W, int ldw,
             float* __restrict__ C, int ldc,
             const float* __restrict__ bias, int K)
{
  __shared__ float As[16][68];
  __shared__ float Ws[16][68];
  const int tid = threadIdx.x;
  const int m0 = blockIdx.y * 64, n0 = blockIdx.x * 64;
  const int lr = tid >> 2, lc = (tid & 3) * 4;
  const float* Ap = A + (size_t)(m0 + lr) * lda + lc;
  const float* Wp = W + (size_t)(n0 + lr) * ldw + lc;
  const int tx = tid & 15, ty = tid >> 4;
  float acc[4][4] = {};
  for (int k0 = 0; k0 < K; k0 += 16){
    float4 a = *(const float4*)(Ap + k0);
    float4 w = *(const float4*)(Wp + k0);
    if (SILU_A){ a.x = siluf(a.x); a.y = siluf(a.y); a.z = siluf(a.z); a.w = siluf(a.w); }
    __syncthreads();
    As[lc+0][lr] = a.x; As[lc+1][lr] = a.y; As[lc+2][lr] = a.z; As[lc+3][lr] = a.w;
    Ws[lc+0][lr] = w.x; Ws[lc+1][lr] = w.y; Ws[lc+2][lr] = w.z; Ws[lc+3][lr] = w.w;
    __syncthreads();
#pragma unroll
    for (int k = 0; k < 16; ++k){
      float4 av = *(const float4*)&As[k][ty*4];
      float4 wv = *(const float4*)&Ws[k][tx*4];
      acc[0][0] += av.x*wv.x; acc[0][1] += av.x*wv.y; acc[0][2] += av.x*wv.z; acc[0][3] += av.x*wv.w;
      acc[1][0] += av.y*wv.x; acc[1][1] += av.y*wv.y; acc[1][2] += av.y*wv.z; acc[1][3] += av.y*wv.w;
      acc[2][0] += av.z*wv.x; acc[2][1] += av.z*wv.y; acc[2][2] += av.z*wv.z; acc[2][3] += av.z*wv.w;
      acc[3][0] += av.w*wv.x; acc[3][1] += av.w*wv.y; acc[3][2] += av.w*wv.z; acc[3][3] += av.w*wv.w;
    }
  }
#pragma unroll
  for (int i = 0; i < 4; ++i){
    float* Crow = C + (size_t)(m0 + ty*4 + i) * ldc + n0 + tx*4;
    float4 r = {acc[i][0], acc[i][1], acc[i][2], acc[i][3]};
    *(float4*)Crow = r;
  }
}

// ================= fp16 MFMA GEMMs, W pre-converted to f16 (ldw = K) =========
// AMODE: 0 = A is f16, 1 = A is f32, 2 = A is f32 + silu
// EPI:   0 = store f32, 1 = accumulate f32, 3 = store f16, 5 = atomicAdd f32

template<int AMODE>
DEV void stage_a(const void* Av, int lda, int m0, int sr, int k0, int sh,
                 int4& av0, int4& av1)
{
  if (AMODE == 0){
    const unsigned short* ag = (const unsigned short*)Av + (size_t)(m0 + sr) * lda + k0 + sh*16;
    av0 = *(const int4*)ag; av1 = *(const int4*)(ag + 8);
  } else {
    const float* ag = (const float*)Av + (size_t)(m0 + sr) * lda + k0 + sh*16;
    float4 a0 = *(const float4*)ag,     a1 = *(const float4*)(ag+4);
    float4 a2 = *(const float4*)(ag+8), a3 = *(const float4*)(ag+12);
    if (AMODE == 2){
      a0.x=siluf(a0.x); a0.y=siluf(a0.y); a0.z=siluf(a0.z); a0.w=siluf(a0.w);
      a1.x=siluf(a1.x); a1.y=siluf(a1.y); a1.z=siluf(a1.z); a1.w=siluf(a1.w);
      a2.x=siluf(a2.x); a2.y=siluf(a2.y); a2.z=siluf(a2.z); a2.w=siluf(a2.w);
      a3.x=siluf(a3.x); a3.y=siluf(a3.y); a3.z=siluf(a3.z); a3.w=siluf(a3.w);
    }
    av0 = (int4){ pk2(a0.x,a0.y), pk2(a0.z,a0.w), pk2(a1.x,a1.y), pk2(a1.z,a1.w) };
    av1 = (int4){ pk2(a2.x,a2.y), pk2(a2.z,a2.w), pk2(a3.x,a3.y), pk2(a3.z,a3.w) };
  }
}

DEV void epi_store(int EPI, void* Cv, size_t off, float v)
{
  if (EPI == 0)      ((float*)Cv)[off] = v;
  else if (EPI == 1) ((float*)Cv)[off] += v;
  else if (EPI == 3) ((unsigned short*)Cv)[off] = f2h(v);
  else               atomicAdd((float*)Cv + off, v);
}

// ---- 128x128 tile ----
template<int AMODE, int EPI>
__global__ __launch_bounds__(256)
void gemm_h128(const void* __restrict__ Av, int lda,
               const unsigned short* __restrict__ W,
               void* __restrict__ Cv, int ldc, int K)
{
  __shared__ unsigned short As[128*40];
  __shared__ unsigned short Bs[128*40];
  const int tid = threadIdx.x;
  const int m0 = blockIdx.y * 128, n0 = blockIdx.x * 128;
  const int wid = tid >> 6, lane = tid & 63;
  const int wm = (wid & 1) * 64, wn = (wid >> 1) * 64;
  const int fr = lane & 15, fk = lane >> 4;
  const int sr = tid >> 1, sh = tid & 1;

  f32x4 acc[4][4];
#pragma unroll
  for (int i = 0; i < 4; ++i)
#pragma unroll
    for (int j = 0; j < 4; ++j)
#pragma unroll
      for (int r = 0; r < 4; ++r) acc[i][j][r] = 0.f;

  for (int k0 = 0; k0 < K; k0 += 32){
    int4 av0, av1;
    stage_a<AMODE>(Av, lda, m0, sr, k0, sh, av0, av1);
    const unsigned short* wg = W + (size_t)(n0 + sr) * K + k0 + sh*16;
    int4 bv0 = *(const int4*)wg, bv1 = *(const int4*)(wg + 8);
    __syncthreads();
    *(int4*)&As[sr*40 + sh*16]     = av0;
    *(int4*)&As[sr*40 + sh*16 + 8] = av1;
    *(int4*)&Bs[sr*40 + sh*16]     = bv0;
    *(int4*)&Bs[sr*40 + sh*16 + 8] = bv1;
    __syncthreads();
    half8 a[4], b[4];
#pragma unroll
    for (int i = 0; i < 4; ++i) a[i] = *(const half8*)&As[(wm + i*16 + fr)*40 + fk*8];
#pragma unroll
    for (int j = 0; j < 4; ++j) b[j] = *(const half8*)&Bs[(wn + j*16 + fr)*40 + fk*8];
#pragma unroll
    for (int i = 0; i < 4; ++i)
#pragma unroll
      for (int j = 0; j < 4; ++j)
        acc[i][j] = __builtin_amdgcn_mfma_f32_16x16x32_f16(a[i], b[j], acc[i][j], 0, 0, 0);
  }
#pragma unroll
  for (int i = 0; i < 4; ++i)
#pragma unroll
    for (int j = 0; j < 4; ++j){
      int col = n0 + wn + j*16 + fr;
#pragma unroll
      for (int r = 0; r < 4; ++r){
        int row = m0 + wm + i*16 + fk*4 + r;
        epi_store(EPI, Cv, (size_t)row * ldc + col, acc[i][j][r]);
      }
    }
}

// ---- 128x64 tile (optionally split-K via blockIdx.z) ----
template<int AMODE, int EPI, int KSPLIT = 1>
__global__ __launch_bounds__(256)
void gemm_h64(const void* __restrict__ Av, int lda,
              const unsigned short* __restrict__ W,
              void* __restrict__ Cv, int ldc, int K)
{
  __shared__ unsigned short As[128*40];
  __shared__ unsigned short Bs[64*40];
  const int tid = threadIdx.x;
  const int m0 = blockIdx.y * 128, n0 = blockIdx.x * 64;
  const int klen = K / KSPLIT, kbase = blockIdx.z * klen;
  const int wid = tid >> 6, lane = tid & 63;
  const int fr = lane & 15, fk = lane >> 4;
  const int sr = tid >> 1, sh = tid & 1;   // A staging
  const int br = tid >> 2, bq = tid & 3;   // B staging

  f32x4 acc[2][4];
#pragma unroll
  for (int i = 0; i < 2; ++i)
#pragma unroll
    for (int j = 0; j < 4; ++j)
#pragma unroll
      for (int r = 0; r < 4; ++r) acc[i][j][r] = 0.f;

  for (int kk = 0; kk < klen; kk += 32){
    int k0 = kbase + kk;
    int4 av0, av1;
    stage_a<AMODE>(Av, lda, m0, sr, k0, sh, av0, av1);
    const unsigned short* wg = W + (size_t)(n0 + br) * K + k0 + bq*8;
    int4 bv0 = *(const int4*)wg;
    __syncthreads();
    *(int4*)&As[sr*40 + sh*16]     = av0;
    *(int4*)&As[sr*40 + sh*16 + 8] = av1;
    *(int4*)&Bs[br*40 + bq*8]      = bv0;
    __syncthreads();
    half8 a[2], b[4];
#pragma unroll
    for (int i = 0; i < 2; ++i) a[i] = *(const half8*)&As[(wid*32 + i*16 + fr)*40 + fk*8];
#pragma unroll
    for (int j = 0; j < 4; ++j) b[j] = *(const half8*)&Bs[(j*16 + fr)*40 + fk*8];
#pragma unroll
    for (int i = 0; i < 2; ++i)
#pragma unroll
      for (int j = 0; j < 4; ++j)
        acc[i][j] = __builtin_amdgcn_mfma_f32_16x16x32_f16(a[i], b[j], acc[i][j], 0, 0, 0);
  }
#pragma unroll
  for (int i = 0; i < 2; ++i)
#pragma unroll
    for (int j = 0; j < 4; ++j){
      int col = n0 + j*16 + fr;
#pragma unroll
      for (int r = 0; r < 4; ++r){
        int row = m0 + wid*32 + i*16 + fk*4 + r;
        epi_store(EPI, Cv, (size_t)row * ldc + col, acc[i][j][r]);
      }
    }
}

// ---------------- Win transpose (64,512) -> (512,64) ----------------
__global__ __launch_bounds__(256)
void transpose_win(const float* __restrict__ Win, float* __restrict__ WinT)
{
  int idx = blockIdx.x * 256 + threadIdx.x;  // 32768
  int n = idx >> 6, k = idx & 63;
  WinT[idx] = Win[(size_t)k * 512 + n];
}

// ---------------- liquid RNN scan v3.1 (pure busy-spin) ----------------
__global__ __launch_bounds__(512)
void liquid_scan3(const float* __restrict__ pre, const float* __restrict__ Wrec,
                  const float* __restrict__ bias, const float* __restrict__ tau,
                  float* __restrict__ xout, float* __restrict__ hbuf,
                  unsigned* __restrict__ flags)
{
  __shared__ float Wl[32800];   // word(k,o) = k*64 + o + (k>>6)*4
  __shared__ float hl[544];     // word(k)   = k + (k>>6)*4
  __shared__ float hnew[64];
  const int tid = threadIdx.x;
  const int bid = blockIdx.x;
  const int slice = bid >> 3, b = bid & 7;
  for (int idx = tid; idx < 512*16; idx += 512){
    int k = idx >> 4, c4 = (idx & 15) * 4;
    float4 w = *(const float4*)(Wrec + (size_t)k*512 + slice*64 + c4);
    *(float4*)&Wl[k*64 + c4 + (k>>6)*4] = w;
  }
  hl[tid + (tid>>6)*4] = 0.f;
  const int o = tid >> 3, kl = tid & 7;
  const int og = slice*64 + o;
  const float tauinv = 1.f / (softplusf(tau[og]) + 0.1f);
  const float bo = bias[og];
  float hold = 0.f;
  const float* preb = pre + (size_t)b * S_ * 512;
  float* xb = xout + (size_t)b * S_ * 512;
  float* hb0 = hbuf + (size_t)b * 512;
  unsigned* bflags = flags + b*8*16;
  unsigned* myflag = bflags + slice*16;
  const int kbase = kl * 64;
  const float* wp = &Wl[(size_t)kbase*64 + o + kl*4];
  __syncthreads();
  for (int t = 0; t < S_; ++t){
    float prev = (kl == 0) ? preb[(size_t)t*512 + og] : 0.f;
    float hreg[64];
#pragma unroll
    for (int j4 = 0; j4 < 16; ++j4)
      *(float4*)&hreg[j4*4] = *(const float4*)&hl[kbase + kl*4 + j4*4];
    float s = 0.f;
#pragma unroll
    for (int j = 0; j < 64; ++j)
      s += hreg[j] * wp[(size_t)j * 64];
    s += __shfl_xor(s, 1);
    s += __shfl_xor(s, 2);
    s += __shfl_xor(s, 4);
    if (kl == 0){
      float act = tanhf(s + prev + bo);
      hold += (act - hold) * tauinv;
      xb[(size_t)t*512 + og] = hold;
      hnew[o] = hold;
    }
    __syncthreads();
    if (tid < 64)
      __hip_atomic_store(hb0 + (t&1)*4096 + slice*64 + tid, hnew[tid],
                         __ATOMIC_RELAXED, __HIP_MEMORY_SCOPE_AGENT);
    if (tid == 0){
      asm volatile("s_waitcnt vmcnt(0)" ::: "memory");
      __hip_atomic_store(myflag, (unsigned)(t+1),
                         __ATOMIC_RELAXED, __HIP_MEMORY_SCOPE_AGENT);
    }
    if (tid < 8){
      while (__hip_atomic_load(bflags + tid*16, __ATOMIC_RELAXED,
                               __HIP_MEMORY_SCOPE_AGENT) < (unsigned)(t+1)) { }
    }
    __syncthreads();
    float hv = __hip_atomic_load(hb0 + (t&1)*4096 + tid,
                                 __ATOMIC_RELAXED, __HIP_MEMORY_SCOPE_AGENT);
    hl[tid + (tid>>6)*4] = hv;
    __syncthreads();
  }
}

// ---------------- causal depthwise conv1d f16 -> f16 ----------------
__global__ __launch_bounds__(256)
void conv_silu(const unsigned short* __restrict__ xz, const float* __restrict__ cw,
               const float* __restrict__ cb, unsigned short* __restrict__ xm)
{
  int idx = blockIdx.x * 256 + threadIdx.x;
  int d = idx & 1023;
  int bs = idx >> 10;
  int t = bs & 511;
  const unsigned short* p = xz + (size_t)bs * 2048 + d;
  float4 w = *(const float4*)(cw + d*4);
  float acc = cb[d] + w.w * h2f(p[0]);
  if (t >= 1) acc += w.z * h2f(p[-2048]);
  if (t >= 2) acc += w.y * h2f(p[-2*2048]);
  if (t >= 3) acc += w.x * h2f(p[-3*2048]);
  xm[idx] = f2h(siluf(acc));
}

// ---------------- fused mamba scan v3: dt_proj fused, f16 xm/z ----------------
__global__ __launch_bounds__(256)
void mamba_scan3(const float* __restrict__ xdbl, const unsigned short* __restrict__ xm,
                 const unsigned short* __restrict__ xz,
                 const float* __restrict__ dt_w, const float* __restrict__ dt_b,
                 const float* __restrict__ A_log, const float* __restrict__ Dp,
                 unsigned short* __restrict__ yg)
{
  const int tid = threadIdx.x;
  const int wave = tid >> 6, lane = tid & 63;
  const int ch = lane >> 3, sub = lane & 7;     // 8 channels/wave, 8 threads/channel
  const int d = blockIdx.x * 32 + wave * 8 + ch;
  const int b = blockIdx.y;
  float2 al = *(const float2*)(A_log + (size_t)d*16 + sub*2);
  const float A0 = -__expf(al.x), A1 = -__expf(al.y);
  const float Dv = Dp[d];
  const float4 wq = *(const float4*)(dt_w + (size_t)d*32 + sub*4);
  const float dtbv = dt_b[d];
  float h0 = 0.f, h1 = 0.f;
  const size_t rb = (size_t)b * S_;
  const float* xdp = xdbl + rb*64;
  const unsigned short* xmp = xm + rb*1024 + d;
  const unsigned short* zp  = xz + rb*2048 + 1024 + d;
  float* dummy;
  unsigned short* yp = yg + rb*1024 + d;
#pragma unroll 2
  for (int t = 0; t < S_; ++t){
    const float* xr = xdp + (size_t)t*64;
    float4 xq = *(const float4*)(xr + sub*4);          // dt_rank slice
    float s = xq.x*wq.x + xq.y*wq.y + xq.z*wq.z + xq.w*wq.w;
    s += __shfl_xor(s, 1);
    s += __shfl_xor(s, 2);
    s += __shfl_xor(s, 4);
    float dtv = softplusf(s + dtbv);
    float xv  = h2f(xmp[(size_t)t*1024]);
    float2 B2 = *(const float2*)(xr + 32 + sub*2);
    float2 C2 = *(const float2*)(xr + 48 + sub*2);
    float cbu = dtv * xv;
    h0 = __expf(dtv * A0) * h0 + cbu * B2.x;
    h1 = __expf(dtv * A1) * h1 + cbu * B2.y;
    float y = h0 * C2.x + h1 * C2.y;
    y += __shfl_xor(y, 1);
    y += __shfl_xor(y, 2);
    y += __shfl_xor(y, 4);
    if (sub == 0){
      float zv = h2f(zp[(size_t)t*2048]);
      yp[(size_t)t*1024] = f2h((y + Dv * xv) * siluf(zv));
    }
  }
}

// ---------------- LayerNorm (512), one wg per row; H: f16 output ----------------
template<bool H>
__global__ __launch_bounds__(256)
void layernorm_k(const float* __restrict__ x, const float* __restrict__ g,
                 const float* __restrict__ b, void* __restrict__ y)
{
  __shared__ float red[8];
  const int row = blockIdx.x, tid = threadIdx.x;
  const float* xr = x + (size_t)row * 512;
  float2 v = *(const float2*)(xr + tid*2);
  float s = v.x + v.y;
#pragma unroll
  for (int o = 32; o; o >>= 1) s += __shfl_xor(s, o);
  if ((tid & 63) == 0) red[tid >> 6] = s;
  __syncthreads();
  float mean = (red[0] + red[1] + red[2] + red[3]) * (1.f/512.f);
  float dx = v.x - mean, dy = v.y - mean;
  float q = dx*dx + dy*dy;
#pragma unroll
  for (int o = 32; o; o >>= 1) q += __shfl_xor(q, o);
  if ((tid & 63) == 0) red[4 + (tid >> 6)] = q;
  __syncthreads();
  float var = (red[4] + red[5] + red[6] + red[7]) * (1.f/512.f);
  float rstd = rsqrtf(var + 1e-5f);
  float2 gg = *(const float2*)(g + tid*2);
  float2 bb = *(const float2*)(b + tid*2);
  float ox = dx*rstd*gg.x + bb.x;
  float oy = dy*rstd*gg.y + bb.y;
  if (H){
    unsigned* yr = (unsigned*)y + (size_t)row*256 + tid;
    *yr = (unsigned)f2h(ox) | ((unsigned)f2h(oy) << 16);
  } else {
    float2 o2 = {ox, oy};
    *(float2*)((float*)y + (size_t)row*512 + tid*2) = o2;
  }
}

// ---------------- B-spline basis -> fp16: (4096,512) -> (4096,512,8) ----------------
__global__ __launch_bounds__(256)
void bspline_kernel(const float* __restrict__ xin, unsigned short* __restrict__ basis)
{
  int idx = blockIdx.x * 256 + threadIdx.x;
  float x = xin[idx];
  float bb[8];
  bspline8(x, bb);
  int4 v = { pk2(bb[0],bb[1]), pk2(bb[2],bb[3]), pk2(bb[4],bb[5]), pk2(bb[6],bb[7]) };
  *(int4*)(basis + (size_t)idx * 8) = v;
}

// ---------------- mean over S ----------------
__global__ __launch_bounds__(512)
void mean_over_s(const float* __restrict__ x, float* __restrict__ out)
{
  int b = blockIdx.x, d = threadIdx.x;
  const float* p = x + (size_t)b*S_*512 + d;
  float s = 0.f;
  for (int t = 0; t < S_; ++t) s += p[(size_t)t*512];
  out[b*512 + d] = s * (1.f/512.f);
}

// ---------------- classifier KAN: (8,512) -> (8,10) ----------------
__global__ __launch_bounds__(64)
void cls_kan(const float* __restrict__ xmean, const float* __restrict__ bw,
             const float* __restrict__ sw, float* __restrict__ out)
{
  int o = blockIdx.x % 10, b = blockIdx.x / 10;
  int lane = threadIdx.x;
  float acc = 0.f;
  for (int i = lane; i < 512; i += 64){
    float xv = xmean[b*512 + i];
    acc += siluf(xv) * bw[o*512 + i];
    float bb[8]; bspline8(xv, bb);
    const float* sp = sw + ((size_t)(o*512 + i)) * 8;
#pragma unroll
    for (int c = 0; c < 8; ++c) acc += bb[c] * sp[c];
  }
#pragma unroll
  for (int off = 32; off; off >>= 1) acc += __shfl_xor(acc, off);
  if (lane == 0) out[b*10 + o] = acc;
}

// ---------------- launch ----------------
extern "C" void kernel_launch(void* const* d_in, const int* in_sizes, int n_in,
                              void* d_out, int out_size, void* d_ws, size_t ws_size,
                              hipStream_t stream)
{
  const float* x_in    = (const float*)d_in[0];
  const float* lq_Win  = (const float*)d_in[1];
  const float* lq_Wrec = (const float*)d_in[2];
  const float* lq_b    = (const float*)d_in[3];
  const float* lq_tau  = (const float*)d_in[4];
  const float* ln_g    = (const float*)d_in[5];
  const float* ln_bi   = (const float*)d_in[6];
  const float* in_proj = (const float*)d_in[7];
  const float* conv_w  = (const float*)d_in[8];
  const float* conv_b  = (const float*)d_in[9];
  const float* x_proj  = (const float*)d_in[10];
  const float* dt_w    = (const float*)d_in[11];
  const float* dt_b    = (const float*)d_in[12];
  const float* A_log   = (const float*)d_in[13];
  const float* Dp      = (const float*)d_in[14];
  const float* out_w   = (const float*)d_in[15];
  const float* kb_w    = (const float*)d_in[16];
  const float* ks_w    = (const float*)d_in[17];
  const float* fn_g    = (const float*)d_in[18];
  const float* fn_b    = (const float*)d_in[19];
  const float* cb_w    = (const float*)d_in[20];
  const float* cs_w    = (const float*)d_in[21];
  float* out = (float*)d_out;

  char* ws = (char*)d_ws;
  float* xcur  = (float*)(ws + OFF_X);
  float* xn32  = (float*)(ws + OFF_XN);
  unsigned short* xn16 = (unsigned short*)(ws + OFF_XN);
  unsigned short* xz16 = (unsigned short*)(ws + OFF_XZ);
  unsigned short* xm16 = (unsigned short*)(ws + OFF_XM);
  float* xdbl  = (float*)(ws + OFF_XDBL);
  unsigned short* yg16 = (unsigned short*)(ws + OFF_YG);
  float* mo    = (float*)(ws + OFF_MO);
  float* wint  = (float*)(ws + OFF_WINT);
  float* xmean = (float*)(ws + OFF_MEAN);
  float* hbufp = (float*)(ws + OFF_HBUF);
  unsigned* flgp = (unsigned*)(ws + OFF_FLG);
  unsigned short* w16 = (unsigned short*)(ws + OFF_W16);
  unsigned short* basis = (unsigned short*)(ws + OFF_BASIS);

  // liquid projection: pre = x @ Win (via WinT), then scan
  transpose_win<<<128, 256, 0, stream>>>(lq_Win, wint);
  gemm_nt<false,0><<<dim3(D_/64, ROWS/64), 256, 0, stream>>>(x_in, IN_, wint, IN_, xn32, D_, nullptr, IN_);
  hipMemsetAsync(flgp, 0, 8*8*16*sizeof(unsigned), stream);
  liquid_scan3<<<64, 512, 0, stream>>>(xn32, lq_Wrec, lq_b, lq_tau, xcur, hbufp, flgp);

  // convert all layer weights to f16 once
  for (int l = 0; l < L_; ++l){
    conv_w16<<<1952, 256, 0, stream>>>(
        in_proj + (size_t)l*2*DI_*D_, out_w + (size_t)l*D_*DI_,
        kb_w + (size_t)l*D_*D_, ks_w + (size_t)l*D_*D_*8,
        x_proj + (size_t)l*64*DI_, w16 + (size_t)l*W_PER_LAYER);
  }

  for (int l = 0; l < L_; ++l){
    const unsigned short* wl = w16 + (size_t)l*W_PER_LAYER;
    layernorm_k<true><<<ROWS, 256, 0, stream>>>(xcur, ln_g + l*D_, ln_bi + l*D_, xn16);
    gemm_h128<0,3><<<dim3(16, 32), 256, 0, stream>>>(
        xn16, D_, wl + W_IP, xz16, 2*DI_, D_);
    conv_silu<<<ROWS*DI_/256, 256, 0, stream>>>(xz16, conv_w + l*DI_*DCONV_, conv_b + l*DI_, xm16);
    hipMemsetAsync(xdbl, 0, (size_t)ROWS*64*sizeof(float), stream);
    gemm_h64<0,5,4><<<dim3(1, 32, 4), 256, 0, stream>>>(
        xm16, DI_, wl + W_XP, xdbl, 64, DI_);
    mamba_scan3<<<dim3(32, 8), 256, 0, stream>>>(
        xdbl, xm16, xz16, dt_w + (size_t)l*DI_*DTR_, dt_b + l*DI_,
        A_log + (size_t)l*DI_*16, Dp + l*DI_, yg16);
    gemm_h64<0,0><<<dim3(8, 32), 256, 0, stream>>>(
        yg16, DI_, wl + W_OP, mo, D_, DI_);
    bspline_kernel<<<ROWS*D_/256, 256, 0, stream>>>(mo, basis);
    gemm_h64<2,1><<<dim3(8, 32), 256, 0, stream>>>(
        mo, D_, wl + W_KB, xcur, D_, D_);
    gemm_h64<0,1><<<dim3(8, 32), 256, 0, stream>>>(
        basis, D_*8, wl + W_KS, xcur, D_, D_*8);
  }

  layernorm_k<false><<<ROWS, 256, 0, stream>>>(xcur, fn_g, fn_b, xn32);
  mean_over_s<<<B_, 512, 0, stream>>>(xn32, xmean);
  cls_kan<<<B_*10, 64, 0, stream>>>(xmean, cb_w, cs_w, out);
}

// Round 9
// 3788.532 us; speedup vs baseline: 1.1200x; 1.1200x over previous
//
#include <hip/hip_runtime.h>
#include <hip/hip_bf16.h>
#include <cmath>

#define DEV __device__ __forceinline__

constexpr int B_ = 8, S_ = 512, IN_ = 64, D_ = 512, L_ = 4;
constexpr int DI_ = 1024, DCONV_ = 4, DTR_ = 32;
constexpr int ROWS = B_ * S_;  // 4096

// ---------------- workspace arena (bytes) ----------------
constexpr size_t MB = 1ull << 20;
constexpr size_t OFF_X    = 0;              // x_cur   (4096,512) f32  8MB
constexpr size_t OFF_XN   = OFF_X   + 8*MB; // xn f16 / final-LN f32   8MB
constexpr size_t OFF_XZ   = OFF_XN  + 8*MB; // xz f16 (4096,2048) 16MB (region 32MB)
constexpr size_t OFF_XM   = OFF_XZ  + 32*MB;// xm f16 (4096,1024)  8MB (region 16MB)
constexpr size_t OFF_DT   = OFF_XM  + 16*MB;// dt f32 (4096,1024) 16MB
constexpr size_t OFF_XDBL = OFF_DT  + 16*MB;// x_dbl  (4096,64) f32 1MB
constexpr size_t OFF_YG   = OFF_XDBL+ 1*MB; // y_gated f16 (4096,1024) 8MB (region 16MB)
constexpr size_t OFF_MO   = OFF_YG  + 16*MB;// mamba_o (4096,512) f32  8MB
constexpr size_t OFF_WINT = OFF_MO  + 8*MB; // WinT    (512,64)        128KB
constexpr size_t OFF_MEAN = OFF_WINT+ 128*1024; // xmean (8,512)       16KB
constexpr size_t OFF_HBUF = OFF_MEAN+ 16*1024;  // hbuf [2][8][512]    32KB
constexpr size_t OFF_FLG  = OFF_HBUF+ 32*1024;  // flags 8*8*16 u32    4KB
constexpr size_t OFF_W16  = OFF_FLG + 64*1024;  // f16 weights 4 layers ~31MB
constexpr size_t OFF_BASIS= OFF_XZ;         // basis f16 (4096,4096) 32MB, aliases xz region

// per-layer f16 weight arena (element offsets)
constexpr size_t W_IP = 0;         // (2048,512)  1048576
constexpr size_t W_OP = 1048576;   // (512,1024)   524288
constexpr size_t W_KB = 1572864;   // (512,512)    262144
constexpr size_t W_KS = 1835008;   // (512,4096)  2097152
constexpr size_t W_XP = 3932160;   // (64,1024)     65536
constexpr size_t W_DT = 3997696;   // (1024,32)     32768
constexpr size_t W_PER_LAYER = 4030464;

// ---------------- math helpers ----------------
DEV float siluf(float x){ return x / (1.f + __expf(-x)); }
DEV float softplusf(float x){ return fmaxf(x, 0.f) + log1pf(__expf(-fabsf(x))); }
DEV unsigned short f2h(float f){ return __builtin_bit_cast(unsigned short, (_Float16)f); }
DEV float h2f(unsigned short u){ return (float)__builtin_bit_cast(_Float16, u); }
DEV int pk2(float a, float b){ return (int)((unsigned)f2h(a) | ((unsigned)f2h(b) << 16)); }

typedef _Float16 half8 __attribute__((ext_vector_type(8)));
typedef float f32x4 __attribute__((ext_vector_type(4)));

DEV void bspline8(float x, float* bb){
  const float h = 0.4f, g0 = -2.2f;
  float b0[11];
#pragma unroll
  for (int j = 0; j < 11; ++j){
    float gj  = g0 + h * j;
    float gj1 = g0 + h * (j + 1);
    b0[j] = (x >= gj && x < gj1) ? 1.f : 0.f;
  }
#pragma unroll
  for (int p = 1; p <= 3; ++p){
    float inv = 1.f / (h * p);
#pragma unroll
    for (int j = 0; j + p < 11; ++j){
      float gj  = g0 + h * j;
      float gip = g0 + h * (j + p + 1);
      b0[j] = (x - gj) * inv * b0[j] + (gip - x) * inv * b0[j + 1];
    }
  }
#pragma unroll
  for (int c = 0; c < 8; ++c) bb[c] = b0[c];
}

// ---------------- weight f32 -> f16 conversion (one layer) ----------------
__global__ __launch_bounds__(256)
void conv_w16(const float* __restrict__ ip, const float* __restrict__ op,
              const float* __restrict__ kb, const float* __restrict__ ks,
              const float* __restrict__ xp, const float* __restrict__ dt,
              unsigned short* __restrict__ w16)
{
  int blk = blockIdx.x, tid = threadIdx.x;
  const float* src; size_t doff; int sb;
  if      (blk < 512) { src = ip; doff = W_IP; sb = blk; }
  else if (blk < 768) { src = op; doff = W_OP; sb = blk - 512; }
  else if (blk < 896) { src = kb; doff = W_KB; sb = blk - 768; }
  else if (blk < 1920){ src = ks; doff = W_KS; sb = blk - 896; }
  else if (blk < 1952){ src = xp; doff = W_XP; sb = blk - 1920; }
  else                { src = dt; doff = W_DT; sb = blk - 1952; }
  size_t e = (size_t)sb * 2048 + tid * 8;
  float4 a = *(const float4*)(src + e), b = *(const float4*)(src + e + 4);
  int4 v = { pk2(a.x,a.y), pk2(a.z,a.w), pk2(b.x,b.y), pk2(b.z,b.w) };
  *(int4*)&w16[doff + e] = v;
}

// ---------------- tiled f32 NT GEMM (initial x@WinT only) ----------------
template<bool SILU_A, int EPI>
__global__ __launch_bounds__(256)
void gemm_nt(const float* __restrict__ A, int lda,
             const float* __restrict__ W, int ldw,
             float* __restrict__ C, int ldc,
             const float* __restrict__ bias, int K)
{
  __shared__ float As[16][68];
  __shared__ float Ws[16][68];
  const int tid = threadIdx.x;
  const int m0 = blockIdx.y * 64, n0 = blockIdx.x * 64;
  const int lr = tid >> 2, lc = (tid & 3) * 4;
  const float* Ap = A + (size_t)(m0 + lr) * lda + lc;
  const float* Wp = W + (size_t)(n0 + lr) * ldw + lc;
  const int tx = tid & 15, ty = tid >> 4;
  float acc[4][4] = {};
  for (int k0 = 0; k0 < K; k0 += 16){
    float4 a = *(const float4*)(Ap + k0);
    float4 w = *(const float4*)(Wp + k0);
    if (SILU_A){ a.x = siluf(a.x); a.y = siluf(a.y); a.z = siluf(a.z); a.w = siluf(a.w); }
    __syncthreads();
    As[lc+0][lr] = a.x; As[lc+1][lr] = a.y; As[lc+2][lr] = a.z; As[lc+3][lr] = a.w;
    Ws[lc+0][lr] = w.x; Ws[lc+1][lr] = w.y; Ws[lc+2][lr] = w.z; Ws[lc+3][lr] = w.w;
    __syncthreads();
#pragma unroll
    for (int k = 0; k < 16; ++k){
      float4 av = *(const float4*)&As[k][ty*4];
      float4 wv = *(const float4*)&Ws[k][tx*4];
      acc[0][0] += av.x*wv.x; acc[0][1] += av.x*wv.y; acc[0][2] += av.x*wv.z; acc[0][3] += av.x*wv.w;
      acc[1][0] += av.y*wv.x; acc[1][1] += av.y*wv.y; acc[1][2] += av.y*wv.z; acc[1][3] += av.y*wv.w;
      acc[2][0] += av.z*wv.x; acc[2][1] += av.z*wv.y; acc[2][2] += av.z*wv.z; acc[2][3] += av.z*wv.w;
      acc[3][0] += av.w*wv.x; acc[3][1] += av.w*wv.y; acc[3][2] += av.w*wv.z; acc[3][3] += av.w*wv.w;
    }
  }
#pragma unroll
  for (int i = 0; i < 4; ++i){
    float* Crow = C + (size_t)(m0 + ty*4 + i) * ldc + n0 + tx*4;
    float4 r = {acc[i][0], acc[i][1], acc[i][2], acc[i][3]};
    *(float4*)Crow = r;
  }
}

// ================= fp16 MFMA GEMMs, W pre-converted to f16 (ldw = K) =========
// AMODE: 0 = A is f16, 1 = A is f32, 2 = A is f32 + silu
// EPI:   0 = store f32, 1 = accumulate f32, 2 = softplus(acc+bias) f32, 3 = store f16

template<int AMODE>
DEV void stage_a(const void* Av, int lda, int m0, int sr, int k0, int sh,
                 int4& av0, int4& av1)
{
  if (AMODE == 0){
    const unsigned short* ag = (const unsigned short*)Av + (size_t)(m0 + sr) * lda + k0 + sh*16;
    av0 = *(const int4*)ag; av1 = *(const int4*)(ag + 8);
  } else {
    const float* ag = (const float*)Av + (size_t)(m0 + sr) * lda + k0 + sh*16;
    float4 a0 = *(const float4*)ag,     a1 = *(const float4*)(ag+4);
    float4 a2 = *(const float4*)(ag+8), a3 = *(const float4*)(ag+12);
    if (AMODE == 2){
      a0.x=siluf(a0.x); a0.y=siluf(a0.y); a0.z=siluf(a0.z); a0.w=siluf(a0.w);
      a1.x=siluf(a1.x); a1.y=siluf(a1.y); a1.z=siluf(a1.z); a1.w=siluf(a1.w);
      a2.x=siluf(a2.x); a2.y=siluf(a2.y); a2.z=siluf(a2.z); a2.w=siluf(a2.w);
      a3.x=siluf(a3.x); a3.y=siluf(a3.y); a3.z=siluf(a3.z); a3.w=siluf(a3.w);
    }
    av0 = (int4){ pk2(a0.x,a0.y), pk2(a0.z,a0.w), pk2(a1.x,a1.y), pk2(a1.z,a1.w) };
    av1 = (int4){ pk2(a2.x,a2.y), pk2(a2.z,a2.w), pk2(a3.x,a3.y), pk2(a3.z,a3.w) };
  }
}

template<int EPI>
DEV void epi_store(void* Cv, size_t off, float v, const float* bias, int col)
{
  if (EPI == 0)      ((float*)Cv)[off] = v;
  else if (EPI == 1) ((float*)Cv)[off] += v;
  else if (EPI == 2) ((float*)Cv)[off] = softplusf(v + bias[col]);
  else               ((unsigned short*)Cv)[off] = f2h(v);
}

// ---- 128x128 tile ----
template<int AMODE, int EPI>
__global__ __launch_bounds__(256)
void gemm_h128(const void* __restrict__ Av, int lda,
               const unsigned short* __restrict__ W,
               void* __restrict__ Cv, int ldc,
               const float* __restrict__ bias, int K)
{
  __shared__ unsigned short As[128*40];
  __shared__ unsigned short Bs[128*40];
  const int tid = threadIdx.x;
  const int m0 = blockIdx.y * 128, n0 = blockIdx.x * 128;
  const int wid = tid >> 6, lane = tid & 63;
  const int wm = (wid & 1) * 64, wn = (wid >> 1) * 64;
  const int fr = lane & 15, fk = lane >> 4;
  const int sr = tid >> 1, sh = tid & 1;

  f32x4 acc[4][4];
#pragma unroll
  for (int i = 0; i < 4; ++i)
#pragma unroll
    for (int j = 0; j < 4; ++j)
#pragma unroll
      for (int r = 0; r < 4; ++r) acc[i][j][r] = 0.f;

  for (int k0 = 0; k0 < K; k0 += 32){
    int4 av0, av1;
    stage_a<AMODE>(Av, lda, m0, sr, k0, sh, av0, av1);
    const unsigned short* wg = W + (size_t)(n0 + sr) * K + k0 + sh*16;
    int4 bv0 = *(const int4*)wg, bv1 = *(const int4*)(wg + 8);
    __syncthreads();
    *(int4*)&As[sr*40 + sh*16]     = av0;
    *(int4*)&As[sr*40 + sh*16 + 8] = av1;
    *(int4*)&Bs[sr*40 + sh*16]     = bv0;
    *(int4*)&Bs[sr*40 + sh*16 + 8] = bv1;
    __syncthreads();
    half8 a[4], b[4];
#pragma unroll
    for (int i = 0; i < 4; ++i) a[i] = *(const half8*)&As[(wm + i*16 + fr)*40 + fk*8];
#pragma unroll
    for (int j = 0; j < 4; ++j) b[j] = *(const half8*)&Bs[(wn + j*16 + fr)*40 + fk*8];
#pragma unroll
    for (int i = 0; i < 4; ++i)
#pragma unroll
      for (int j = 0; j < 4; ++j)
        acc[i][j] = __builtin_amdgcn_mfma_f32_16x16x32_f16(a[i], b[j], acc[i][j], 0, 0, 0);
  }
#pragma unroll
  for (int i = 0; i < 4; ++i)
#pragma unroll
    for (int j = 0; j < 4; ++j){
      int col = n0 + wn + j*16 + fr;
#pragma unroll
      for (int r = 0; r < 4; ++r){
        int row = m0 + wm + i*16 + fk*4 + r;
        epi_store<EPI>(Cv, (size_t)row * ldc + col, acc[i][j][r], bias, col);
      }
    }
}

// ---- 128x64 tile ----
template<int AMODE, int EPI>
__global__ __launch_bounds__(256)
void gemm_h64(const void* __restrict__ Av, int lda,
              const unsigned short* __restrict__ W,
              void* __restrict__ Cv, int ldc,
              const float* __restrict__ bias, int K)
{
  __shared__ unsigned short As[128*40];
  __shared__ unsigned short Bs[64*40];
  const int tid = threadIdx.x;
  const int m0 = blockIdx.y * 128, n0 = blockIdx.x * 64;
  const int wid = tid >> 6, lane = tid & 63;
  const int fr = lane & 15, fk = lane >> 4;
  const int sr = tid >> 1, sh = tid & 1;   // A staging
  const int br = tid >> 2, bq = tid & 3;   // B staging

  f32x4 acc[2][4];
#pragma unroll
  for (int i = 0; i < 2; ++i)
#pragma unroll
    for (int j = 0; j < 4; ++j)
#pragma unroll
      for (int r = 0; r < 4; ++r) acc[i][j][r] = 0.f;

  for (int k0 = 0; k0 < K; k0 += 32){
    int4 av0, av1;
    stage_a<AMODE>(Av, lda, m0, sr, k0, sh, av0, av1);
    const unsigned short* wg = W + (size_t)(n0 + br) * K + k0 + bq*8;
    int4 bv0 = *(const int4*)wg;
    __syncthreads();
    *(int4*)&As[sr*40 + sh*16]     = av0;
    *(int4*)&As[sr*40 + sh*16 + 8] = av1;
    *(int4*)&Bs[br*40 + bq*8]      = bv0;
    __syncthreads();
    half8 a[2], b[4];
#pragma unroll
    for (int i = 0; i < 2; ++i) a[i] = *(const half8*)&As[(wid*32 + i*16 + fr)*40 + fk*8];
#pragma unroll
    for (int j = 0; j < 4; ++j) b[j] = *(const half8*)&Bs[(j*16 + fr)*40 + fk*8];
#pragma unroll
    for (int i = 0; i < 2; ++i)
#pragma unroll
      for (int j = 0; j < 4; ++j)
        acc[i][j] = __builtin_amdgcn_mfma_f32_16x16x32_f16(a[i], b[j], acc[i][j], 0, 0, 0);
  }
#pragma unroll
  for (int i = 0; i < 2; ++i)
#pragma unroll
    for (int j = 0; j < 4; ++j){
      int col = n0 + j*16 + fr;
#pragma unroll
      for (int r = 0; r < 4; ++r){
        int row = m0 + wid*32 + i*16 + fk*4 + r;
        epi_store<EPI>(Cv, (size_t)row * ldc + col, acc[i][j][r], bias, col);
      }
    }
}

// ---------------- Win transpose (64,512) -> (512,64) ----------------
__global__ __launch_bounds__(256)
void transpose_win(const float* __restrict__ Win, float* __restrict__ WinT)
{
  int idx = blockIdx.x * 256 + threadIdx.x;  // 32768
  int n = idx >> 6, k = idx & 63;
  WinT[idx] = Win[(size_t)k * 512 + n];
}

// ---------------- liquid RNN scan v3.1 (pure busy-spin) ----------------
__global__ __launch_bounds__(512)
void liquid_scan3(const float* __restrict__ pre, const float* __restrict__ Wrec,
                  const float* __restrict__ bias, const float* __restrict__ tau,
                  float* __restrict__ xout, float* __restrict__ hbuf,
                  unsigned* __restrict__ flags)
{
  __shared__ float Wl[32800];   // word(k,o) = k*64 + o + (k>>6)*4
  __shared__ float hl[544];     // word(k)   = k + (k>>6)*4
  __shared__ float hnew[64];
  const int tid = threadIdx.x;
  const int bid = blockIdx.x;
  const int slice = bid >> 3, b = bid & 7;
  for (int idx = tid; idx < 512*16; idx += 512){
    int k = idx >> 4, c4 = (idx & 15) * 4;
    float4 w = *(const float4*)(Wrec + (size_t)k*512 + slice*64 + c4);
    *(float4*)&Wl[k*64 + c4 + (k>>6)*4] = w;
  }
  hl[tid + (tid>>6)*4] = 0.f;
  const int o = tid >> 3, kl = tid & 7;
  const int og = slice*64 + o;
  const float tauinv = 1.f / (softplusf(tau[og]) + 0.1f);
  const float bo = bias[og];
  float hold = 0.f;
  const float* preb = pre + (size_t)b * S_ * 512;
  float* xb = xout + (size_t)b * S_ * 512;
  float* hb0 = hbuf + (size_t)b * 512;
  unsigned* bflags = flags + b*8*16;
  unsigned* myflag = bflags + slice*16;
  const int kbase = kl * 64;
  const float* wp = &Wl[(size_t)kbase*64 + o + kl*4];
  __syncthreads();
  for (int t = 0; t < S_; ++t){
    float prev = (kl == 0) ? preb[(size_t)t*512 + og] : 0.f;
    float hreg[64];
#pragma unroll
    for (int j4 = 0; j4 < 16; ++j4)
      *(float4*)&hreg[j4*4] = *(const float4*)&hl[kbase + kl*4 + j4*4];
    float s = 0.f;
#pragma unroll
    for (int j = 0; j < 64; ++j)
      s += hreg[j] * wp[(size_t)j * 64];
    s += __shfl_xor(s, 1);
    s += __shfl_xor(s, 2);
    s += __shfl_xor(s, 4);
    if (kl == 0){
      float act = tanhf(s + prev + bo);
      hold += (act - hold) * tauinv;
      xb[(size_t)t*512 + og] = hold;
      hnew[o] = hold;
    }
    __syncthreads();
    if (tid < 64)
      __hip_atomic_store(hb0 + (t&1)*4096 + slice*64 + tid, hnew[tid],
                         __ATOMIC_RELAXED, __HIP_MEMORY_SCOPE_AGENT);
    if (tid == 0){
      asm volatile("s_waitcnt vmcnt(0)" ::: "memory");
      __hip_atomic_store(myflag, (unsigned)(t+1),
                         __ATOMIC_RELAXED, __HIP_MEMORY_SCOPE_AGENT);
    }
    if (tid < 8){
      while (__hip_atomic_load(bflags + tid*16, __ATOMIC_RELAXED,
                               __HIP_MEMORY_SCOPE_AGENT) < (unsigned)(t+1)) { }
    }
    __syncthreads();
    float hv = __hip_atomic_load(hb0 + (t&1)*4096 + tid,
                                 __ATOMIC_RELAXED, __HIP_MEMORY_SCOPE_AGENT);
    hl[tid + (tid>>6)*4] = hv;
    __syncthreads();
  }
}

// ---------------- causal depthwise conv1d f16 -> f16 ----------------
__global__ __launch_bounds__(256)
void conv_silu(const unsigned short* __restrict__ xz, const float* __restrict__ cw,
               const float* __restrict__ cb, unsigned short* __restrict__ xm)
{
  int idx = blockIdx.x * 256 + threadIdx.x;
  int d = idx & 1023;
  int bs = idx >> 10;
  int t = bs & 511;
  const unsigned short* p = xz + (size_t)bs * 2048 + d;
  float4 w = *(const float4*)(cw + d*4);
  float acc = cb[d] + w.w * h2f(p[0]);
  if (t >= 1) acc += w.z * h2f(p[-2048]);
  if (t >= 2) acc += w.y * h2f(p[-2*2048]);
  if (t >= 3) acc += w.x * h2f(p[-3*2048]);
  xm[idx] = f2h(siluf(acc));
}

// ---------------- fused mamba scan (dt from buffer, f16 xm/z) ----------------
__global__ __launch_bounds__(256)
void mamba_scan2(const float* __restrict__ dt, const unsigned short* __restrict__ xm,
                 const float* __restrict__ xdbl, const unsigned short* __restrict__ xz,
                 const float* __restrict__ A_log, const float* __restrict__ Dp,
                 unsigned short* __restrict__ yg)
{
  const int tid = threadIdx.x;
  const int wave = tid >> 6, lane = tid & 63;
  const int ch = lane >> 3, sub = lane & 7;     // 8 channels/wave, 8 threads/channel
  const int d = blockIdx.x * 32 + wave * 8 + ch;
  const int b = blockIdx.y;
  float2 al = *(const float2*)(A_log + (size_t)d*16 + sub*2);
  const float A0 = -__expf(al.x), A1 = -__expf(al.y);
  const float Dv = Dp[d];
  float h0 = 0.f, h1 = 0.f;
  const size_t rb = (size_t)b * S_;
  const float* dtp = dt + rb*1024 + d;
  const unsigned short* xmp = xm + rb*1024 + d;
  const unsigned short* zp  = xz + rb*2048 + 1024 + d;
  const float* bcp = xdbl + rb*64 + 32 + sub*2;
  const float* ccp = xdbl + rb*64 + 48 + sub*2;
  unsigned short* yp = yg + rb*1024 + d;
#pragma unroll 2
  for (int t = 0; t < S_; ++t){
    float dtv = dtp[(size_t)t*1024];
    float xv  = h2f(xmp[(size_t)t*1024]);
    float2 B2 = *(const float2*)(bcp + (size_t)t*64);
    float2 C2 = *(const float2*)(ccp + (size_t)t*64);
    float cbu = dtv * xv;
    h0 = __expf(dtv * A0) * h0 + cbu * B2.x;
    h1 = __expf(dtv * A1) * h1 + cbu * B2.y;
    float y = h0 * C2.x + h1 * C2.y;
    y += __shfl_xor(y, 1);
    y += __shfl_xor(y, 2);
    y += __shfl_xor(y, 4);
    if (sub == 0){
      float zv = h2f(zp[(size_t)t*2048]);
      yp[(size_t)t*1024] = f2h((y + Dv * xv) * siluf(zv));
    }
  }
}

// ---------------- LayerNorm (512), one wg per row; H: f16 output ----------------
template<bool H>
__global__ __launch_bounds__(256)
void layernorm_k(const float* __restrict__ x, const float* __restrict__ g,
                 const float* __restrict__ b, void* __restrict__ y)
{
  __shared__ float red[8];
  const int row = blockIdx.x, tid = threadIdx.x;
  const float* xr = x + (size_t)row * 512;
  float2 v = *(const float2*)(xr + tid*2);
  float s = v.x + v.y;
#pragma unroll
  for (int o = 32; o; o >>= 1) s += __shfl_xor(s, o);
  if ((tid & 63) == 0) red[tid >> 6] = s;
  __syncthreads();
  float mean = (red[0] + red[1] + red[2] + red[3]) * (1.f/512.f);
  float dx = v.x - mean, dy = v.y - mean;
  float q = dx*dx + dy*dy;
#pragma unroll
  for (int o = 32; o; o >>= 1) q += __shfl_xor(q, o);
  if ((tid & 63) == 0) red[4 + (tid >> 6)] = q;
  __syncthreads();
  float var = (red[4] + red[5] + red[6] + red[7]) * (1.f/512.f);
  float rstd = rsqrtf(var + 1e-5f);
  float2 gg = *(const float2*)(g + tid*2);
  float2 bb = *(const float2*)(b + tid*2);
  float ox = dx*rstd*gg.x + bb.x;
  float oy = dy*rstd*gg.y + bb.y;
  if (H){
    unsigned* yr = (unsigned*)y + (size_t)row*256 + tid;
    *yr = (unsigned)f2h(ox) | ((unsigned)f2h(oy) << 16);
  } else {
    float2 o2 = {ox, oy};
    *(float2*)((float*)y + (size_t)row*512 + tid*2) = o2;
  }
}

// ---------------- B-spline basis -> fp16: (4096,512) -> (4096,512,8) ----------------
__global__ __launch_bounds__(256)
void bspline_kernel(const float* __restrict__ xin, unsigned short* __restrict__ basis)
{
  int idx = blockIdx.x * 256 + threadIdx.x;
  float x = xin[idx];
  float bb[8];
  bspline8(x, bb);
  int4 v = { pk2(bb[0],bb[1]), pk2(bb[2],bb[3]), pk2(bb[4],bb[5]), pk2(bb[6],bb[7]) };
  *(int4*)(basis + (size_t)idx * 8) = v;
}

// ---------------- mean over S ----------------
__global__ __launch_bounds__(512)
void mean_over_s(const float* __restrict__ x, float* __restrict__ out)
{
  int b = blockIdx.x, d = threadIdx.x;
  const float* p = x + (size_t)b*S_*512 + d;
  float s = 0.f;
  for (int t = 0; t < S_; ++t) s += p[(size_t)t*512];
  out[b*512 + d] = s * (1.f/512.f);
}

// ---------------- classifier KAN: (8,512) -> (8,10) ----------------
__global__ __launch_bounds__(64)
void cls_kan(const float* __restrict__ xmean, const float* __restrict__ bw,
             const float* __restrict__ sw, float* __restrict__ out)
{
  int o = blockIdx.x % 10, b = blockIdx.x / 10;
  int lane = threadIdx.x;
  float acc = 0.f;
  for (int i = lane; i < 512; i += 64){
    float xv = xmean[b*512 + i];
    acc += siluf(xv) * bw[o*512 + i];
    float bb[8]; bspline8(xv, bb);
    const float* sp = sw + ((size_t)(o*512 + i)) * 8;
#pragma unroll
    for (int c = 0; c < 8; ++c) acc += bb[c] * sp[c];
  }
#pragma unroll
  for (int off = 32; off; off >>= 1) acc += __shfl_xor(acc, off);
  if (lane == 0) out[b*10 + o] = acc;
}

// ---------------- launch ----------------
extern "C" void kernel_launch(void* const* d_in, const int* in_sizes, int n_in,
                              void* d_out, int out_size, void* d_ws, size_t ws_size,
                              hipStream_t stream)
{
  const float* x_in    = (const float*)d_in[0];
  const float* lq_Win  = (const float*)d_in[1];
  const float* lq_Wrec = (const float*)d_in[2];
  const float* lq_b    = (const float*)d_in[3];
  const float* lq_tau  = (const float*)d_in[4];
  const float* ln_g    = (const float*)d_in[5];
  const float* ln_bi   = (const float*)d_in[6];
  const float* in_proj = (const float*)d_in[7];
  const float* conv_w  = (const float*)d_in[8];
  const float* conv_b  = (const float*)d_in[9];
  const float* x_proj  = (const float*)d_in[10];
  const float* dt_w    = (const float*)d_in[11];
  const float* dt_b    = (const float*)d_in[12];
  const float* A_log   = (const float*)d_in[13];
  const float* Dp      = (const float*)d_in[14];
  const float* out_w   = (const float*)d_in[15];
  const float* kb_w    = (const float*)d_in[16];
  const float* ks_w    = (const float*)d_in[17];
  const float* fn_g    = (const float*)d_in[18];
  const float* fn_b    = (const float*)d_in[19];
  const float* cb_w    = (const float*)d_in[20];
  const float* cs_w    = (const float*)d_in[21];
  float* out = (float*)d_out;

  char* ws = (char*)d_ws;
  float* xcur  = (float*)(ws + OFF_X);
  float* xn32  = (float*)(ws + OFF_XN);
  unsigned short* xn16 = (unsigned short*)(ws + OFF_XN);
  unsigned short* xz16 = (unsigned short*)(ws + OFF_XZ);
  unsigned short* xm16 = (unsigned short*)(ws + OFF_XM);
  float* dtb   = (float*)(ws + OFF_DT);
  float* xdbl  = (float*)(ws + OFF_XDBL);
  unsigned short* yg16 = (unsigned short*)(ws + OFF_YG);
  float* mo    = (float*)(ws + OFF_MO);
  float* wint  = (float*)(ws + OFF_WINT);
  float* xmean = (float*)(ws + OFF_MEAN);
  float* hbufp = (float*)(ws + OFF_HBUF);
  unsigned* flgp = (unsigned*)(ws + OFF_FLG);
  unsigned short* w16 = (unsigned short*)(ws + OFF_W16);
  unsigned short* basis = (unsigned short*)(ws + OFF_BASIS);

  // liquid projection: pre = x @ Win (via WinT), then scan
  transpose_win<<<128, 256, 0, stream>>>(lq_Win, wint);
  gemm_nt<false,0><<<dim3(D_/64, ROWS/64), 256, 0, stream>>>(x_in, IN_, wint, IN_, xn32, D_, nullptr, IN_);
  hipMemsetAsync(flgp, 0, 8*8*16*sizeof(unsigned), stream);
  liquid_scan3<<<64, 512, 0, stream>>>(xn32, lq_Wrec, lq_b, lq_tau, xcur, hbufp, flgp);

  // convert all layer weights to f16 once
  for (int l = 0; l < L_; ++l){
    conv_w16<<<1968, 256, 0, stream>>>(
        in_proj + (size_t)l*2*DI_*D_, out_w + (size_t)l*D_*DI_,
        kb_w + (size_t)l*D_*D_, ks_w + (size_t)l*D_*D_*8,
        x_proj + (size_t)l*64*DI_, dt_w + (size_t)l*DI_*DTR_,
        w16 + (size_t)l*W_PER_LAYER);
  }

  for (int l = 0; l < L_; ++l){
    const unsigned short* wl = w16 + (size_t)l*W_PER_LAYER;
    layernorm_k<true><<<ROWS, 256, 0, stream>>>(xcur, ln_g + l*D_, ln_bi + l*D_, xn16);
    gemm_h128<0,3><<<dim3(16, 32), 256, 0, stream>>>(
        xn16, D_, wl + W_IP, xz16, 2*DI_, nullptr, D_);
    conv_silu<<<ROWS*DI_/256, 256, 0, stream>>>(xz16, conv_w + l*DI_*DCONV_, conv_b + l*DI_, xm16);
    gemm_h64<0,0><<<dim3(1, 32), 256, 0, stream>>>(
        xm16, DI_, wl + W_XP, xdbl, 64, nullptr, DI_);
    gemm_h64<1,2><<<dim3(16, 32), 256, 0, stream>>>(
        xdbl, 64, wl + W_DT, dtb, DI_, dt_b + l*DI_, DTR_);
    mamba_scan2<<<dim3(32, 8), 256, 0, stream>>>(
        dtb, xm16, xdbl, xz16, A_log + (size_t)l*DI_*16, Dp + l*DI_, yg16);
    gemm_h64<0,0><<<dim3(8, 32), 256, 0, stream>>>(
        yg16, DI_, wl + W_OP, mo, D_, nullptr, DI_);
    bspline_kernel<<<ROWS*D_/256, 256, 0, stream>>>(mo, basis);
    gemm_h64<2,1><<<dim3(8, 32), 256, 0, stream>>>(
        mo, D_, wl + W_KB, xcur, D_, nullptr, D_);
    gemm_h64<0,1><<<dim3(8, 32), 256, 0, stream>>>(
        basis, D_*8, wl + W_KS, xcur, D_, nullptr, D_*8);
  }

  layernorm_k<false><<<ROWS, 256, 0, stream>>>(xcur, fn_g, fn_b, xn32);
  mean_over_s<<<B_, 512, 0, stream>>>(xn32, xmean);
  cls_kan<<<B_*10, 64, 0, stream>>>(xmean, cb_w, cs_w, out);
}